// Round 11
// baseline (345.968 us; speedup 1.0000x reference)
//
#include <hip/hip_runtime.h>
#include <hip/hip_bf16.h>

// Problem constants
#define BATCH 4096
#define IN_SZ 512
#define HID_SZ 2048
#define OUT_SZ 512
#define NLAYER 4
#define INNER 2560        // 512 + 2048
#define NKT (INNER / 64)  // 40 K-tiles of 64

// GEMM tile: BM=128 x BN=160, BK=64; grid 32x16 = 512 blocks = 2/CU.
// 256 threads = 4 waves (2M x 2N), per-wave 64x80.
// THIS ROUND: B operand comes from a FRAGMENT-LINEAR PACKED weight layout
// (built during the mandatory fp32->bf16 conversion). Each B-fragment
// (n16, kt, kk) is one contiguous 1024B chunk: lane l's 16B at chunk+l*16
// holds W[n16*16+(l&15)][kt*64+kk*32+(l>>4)*8 ..+8]. B-loads are single
// coalesced global_load_dwordx4 from L2 (panel 0.8MB/XCD). LDS holds only
// A (2 x 16KB). Per-CU/K-tile: MFMA 1552 cyc >> LDS ~1000, L2-B ~730 ->
// MFMA-bound. R7's failure was the UNPACKED gather (64 lines/load), not
// the B-in-regs idea.

typedef __attribute__((ext_vector_type(8))) short bf16x8;
typedef __attribute__((ext_vector_type(8))) unsigned short u16x8;
typedef __attribute__((ext_vector_type(4))) float f32x4;

__device__ __forceinline__ unsigned short f2bf(float f) {
  unsigned int u = __float_as_uint(f);
  u += 0x7fff + ((u >> 16) & 1);  // RNE
  return (unsigned short)(u >> 16);
}

__device__ __forceinline__ void gload16(const void* g, void* l) {
  __builtin_amdgcn_global_load_lds(
      (const __attribute__((address_space(1))) unsigned int*)g,
      (__attribute__((address_space(3))) unsigned int*)l,
      16, 0, 0);
}

// ---------------- pack kernel: fp32 W -> fragment-linear bf16 ----------------
// Unit i = one 16B chunk-lane: l=i&63, c=i>>6, kk=c&1, kt=(c>>1)%NKT,
// n16=(c>>1)/NKT. Content: W[n16*16+(l&15)][kt*64+kk*32+(l>>4)*8 + 0..7].
// Row source: row < split ? srcA[row] : srcB[row-split] (head fusion).
__global__ void pack_w(const float* __restrict__ srcA, const float* __restrict__ srcB,
                       int split, int nrows, unsigned short* __restrict__ dst) {
  const long nunits = (long)nrows * 320;  // nrows*INNER/8
  long i = (long)blockIdx.x * blockDim.x + threadIdx.x;
  const long stride = (long)gridDim.x * blockDim.x;
  for (; i < nunits; i += stride) {
    const int l = (int)(i & 63);
    const long c2 = i >> 7;           // (i>>6)>>1
    const int kk = (int)((i >> 6) & 1);
    const int kt = (int)(c2 % NKT);
    const long n16 = c2 / NKT;
    const long row = n16 * 16 + (l & 15);
    const int k = kt * 64 + kk * 32 + ((l >> 4) * 8);
    const float* src = (row < split) ? (srcA + row * INNER + k)
                                     : (srcB + (row - split) * (long)INNER + k);
    float4 v0 = *reinterpret_cast<const float4*>(src);
    float4 v1 = *reinterpret_cast<const float4*>(src + 4);
    u16x8 o;
    o[0] = f2bf(v0.x); o[1] = f2bf(v0.y); o[2] = f2bf(v0.z); o[3] = f2bf(v0.w);
    o[4] = f2bf(v1.x); o[5] = f2bf(v1.y); o[6] = f2bf(v1.z); o[7] = f2bf(v1.w);
    *reinterpret_cast<u16x8*>(dst + i * 8) = o;
  }
}

__global__ void build_combined(const float* __restrict__ x,
                               const float* __restrict__ h,
                               unsigned short* __restrict__ out) {
  const int n4 = BATCH * INNER / 4;
  int i = blockIdx.x * blockDim.x + threadIdx.x;
  const int stride = gridDim.x * blockDim.x;
  for (; i < n4; i += stride) {
    int row = i / (INNER / 4);
    int c4 = i - row * (INNER / 4);
    const float* src = (c4 < IN_SZ / 4) ? (x + (long)row * IN_SZ + c4 * 4)
                                        : (h + (long)row * HID_SZ + (c4 - IN_SZ / 4) * 4);
    float4 v = *reinterpret_cast<const float4*>(src);
    ushort4 o;
    o.x = f2bf(v.x); o.y = f2bf(v.y); o.z = f2bf(v.z); o.w = f2bf(v.w);
    *reinterpret_cast<ushort4*>(out + (long)i * 4) = o;
  }
}

// ---------------- 128x160 packed-B GEMM: C = act(A * B^T + bias) ------------
// A: [4096][2560] bf16 row-major (LDS-staged, XOR-swizzled).
// Wp: packed fragment-linear (see pack_w).
// Per K-tile per wave: 4 gload_lds (A stage T+1), 10 coalesced b128 global
// (B frags T+1 -> regs, ping-pong by parity), 8 ds_read_b128 (A frags T),
// 40 MFMA. One vmcnt(0)+barrier per K-tile (VMEM issued a full tile ahead).

#define STAGE_A4(kt, buf) do {                                                \
  _Pragma("unroll")                                                           \
  for (int u_ = 0; u_ < 4; ++u_) {                                            \
    const int base_ = u_ * 32 + w * 8;                                        \
    gload16(A + (long)(row0 + base_ + srow) * INNER + (kt) * 64 + srcsw,      \
            (void*)(&lds[buf][base_ * 64]));                                  \
  } } while (0)

#define LOAD_AF(dst, mh, buf) do {                                           \
  const unsigned short* Ar_ = &lds[buf][0];                                  \
  _Pragma("unroll")                                                          \
  for (int m_ = 0; m_ < 2; ++m_) {                                           \
    int r_ = wr * 64 + (mh) * 32 + m_ * 16 + fr;                             \
    dst[m_][0] = *(const bf16x8*)(Ar_ + r_ * 64 + csw0);                     \
    dst[m_][1] = *(const bf16x8*)(Ar_ + r_ * 64 + csw1);                     \
  } } while (0)

// B fragments from packed layout: elem offset n*40960 + kt*1024 + kk*512
// (Bp already includes the wave's n16 base and lane*8).
#define LOAD_BP(dst, kt) do {                                                \
  _Pragma("unroll")                                                          \
  for (int n_ = 0; n_ < 5; ++n_) {                                           \
    dst[n_][0] = *(const bf16x8*)(Bp + n_ * 40960 + (kt) * 1024);            \
    dst[n_][1] = *(const bf16x8*)(Bp + n_ * 40960 + (kt) * 1024 + 512);      \
  } } while (0)

#define MF_HALF(af, bq, mh) do {                                              \
  __builtin_amdgcn_s_setprio(1);                                              \
  _Pragma("unroll")                                                           \
  for (int m_ = 0; m_ < 2; ++m_)                                              \
    _Pragma("unroll")                                                         \
    for (int n_ = 0; n_ < 5; ++n_) {                                          \
      acc[(mh) * 2 + m_][n_] = __builtin_amdgcn_mfma_f32_16x16x32_bf16(       \
          af[m_][0], bq[n_][0], acc[(mh) * 2 + m_][n_], 0, 0, 0);             \
      acc[(mh) * 2 + m_][n_] = __builtin_amdgcn_mfma_f32_16x16x32_bf16(       \
          af[m_][1], bq[n_][1], acc[(mh) * 2 + m_][n_], 0, 0, 0);             \
    }                                                                         \
  __builtin_amdgcn_s_setprio(0);                                              \
} while (0)

#define SB() __builtin_amdgcn_sched_barrier(0)

// Tile body. d = parity (compile-time); BC = current B reg set, BN = next.
// Hazards: STAGE into d^1 is safe (its readers finished before the barrier
// ending tile T-1). End-of-tile vmcnt(0)+barrier makes T+1's A visible to
// all waves and guarantees all tile-T LDS reads retired before T+1's
// restage of buf d. B-reg WAR handled by compiler (full dep info).
#define TILE_BODY(d, BC, BN) do {                                             \
  const int T = T2 + (d);                                                     \
  const int kt1 = (T + 1 < NKT) ? T + 1 : NKT - 1;  /* clamp: dup, benign */  \
  STAGE_A4(kt1, (d) ^ 1);                                                     \
  LOAD_BP(BN, kt1);                                                           \
  LOAD_AF(afL, 0, d);                                                         \
  SB();                                                                       \
  LOAD_AF(afH, 1, d);                                                         \
  SB();                                                                       \
  asm volatile("s_waitcnt lgkmcnt(4)" ::: "memory");  /* afL ready */         \
  SB();                                                                       \
  MF_HALF(afL, BC, 0);                                                        \
  asm volatile("s_waitcnt lgkmcnt(0)" ::: "memory");  /* afH ready */         \
  SB();                                                                       \
  MF_HALF(afH, BC, 1);                                                        \
  asm volatile("s_waitcnt vmcnt(0)" ::: "memory");  /* T+1 A+B landed */      \
  __builtin_amdgcn_s_barrier();                                               \
} while (0)

template <int MODE>
__global__ __launch_bounds__(256, 2)
void gemm_bp(const unsigned short* __restrict__ A, const unsigned short* __restrict__ Wp,
             const float* __restrict__ bias0, const float* __restrict__ bias1,
             void* __restrict__ C) {
  __shared__ unsigned short lds[2][8192];  // 32 KiB: two A-tile buffers

  const int tid = threadIdx.x;
  const int w = tid >> 6;   // 4 waves
  const int lane = tid & 63;

  // XCD mapping: 512 blocks; each XCD owns 2 adjacent 160-col B panels.
  // Co-resident pair (flat, flat+256) shares nb -> shared L1/L2 B slices.
  const int flat = blockIdx.x;
  const int xcd = flat & 7;
  const int local = flat >> 3;           // 0..63
  const int nb = xcd * 2 + (local & 1);  // 16 N-blocks
  const int mb = local >> 1;             // 32 M-blocks
  const int row0 = mb * 128;
  const int col0 = nb * 160;
  const int wr = w >> 1, wcn = w & 1;

  // stage source swizzle (elements): inverse of LDS read swizzle
  const int srow = lane >> 3;
  const int srcsw = ((((lane & 7) << 4) ^ ((lane >> 3) << 4)) >> 1);

  // fragment read addressing
  const int fr = lane & 15;
  const int csw0 = ((((lane >> 4) << 4)) ^ ((lane & 7) << 4)) >> 1;       // kk=0
  const int csw1 = ((64 + ((lane >> 4) << 4)) ^ ((lane & 7) << 4)) >> 1;  // kk=1

  // packed-B base for this wave+lane: n16 = nb*10 + wcn*5 (+n), lane*8 elems
  const unsigned short* Bp = Wp + (long)(nb * 10 + wcn * 5) * 40960 + lane * 8;

  f32x4 acc[4][5] = {};
  bf16x8 afL[2][2], afH[2][2];
  bf16x8 bq0[5][2], bq1[5][2];

  // prologue: A(0) -> buf0, B(0) -> bq0
  STAGE_A4(0, 0);
  LOAD_BP(bq0, 0);
  asm volatile("s_waitcnt vmcnt(0)" ::: "memory");
  __builtin_amdgcn_s_barrier();
  SB();

  for (int T2 = 0; T2 < NKT; T2 += 2) {
    TILE_BODY(0, bq0, bq1);
    TILE_BODY(1, bq1, bq0);
  }
  asm volatile("s_waitcnt vmcnt(0)" ::: "memory");

  // epilogue: C/D layout col = lane&15, row = (lane>>4)*4 + j
  const int erow = row0 + wr * 64 + ((lane >> 4) << 2);
  const int ecol = col0 + wcn * 80 + fr;
  if (MODE == 0) {
    unsigned short* Co = (unsigned short*)C;
#pragma unroll
    for (int n = 0; n < 5; ++n) {
      const int col = ecol + n * 16;
      const float bv = bias0[col];
#pragma unroll
      for (int m = 0; m < 4; ++m) {
        const int row = erow + m * 16;
#pragma unroll
        for (int j = 0; j < 4; ++j) {
          float v = acc[m][n][j] + bv;
          v = fmaxf(v, 0.0f);
          Co[(long)(row + j) * INNER + col] = f2bf(v);
        }
      }
    }
  } else {
    float* outO = (float*)C;                          // [4096,512]
    float* outH = (float*)C + (long)BATCH * OUT_SZ;   // [4096,2048]
#pragma unroll
    for (int n = 0; n < 5; ++n) {
      const int col = ecol + n * 16;
      if (col < OUT_SZ) {
        const float bv = bias0[col];
#pragma unroll
        for (int m = 0; m < 4; ++m) {
          const int row = erow + m * 16;
#pragma unroll
          for (int j = 0; j < 4; ++j)
            outO[(long)(row + j) * OUT_SZ + col] = acc[m][n][j] + bv;
        }
      } else {
        const int hc = col - OUT_SZ;
        const float bv = bias1[hc];
#pragma unroll
        for (int m = 0; m < 4; ++m) {
          const int row = erow + m * 16;
#pragma unroll
          for (int j = 0; j < 4; ++j)
            outH[(long)(row + j) * HID_SZ + hc] = tanhf(acc[m][n][j] + bv);
        }
      }
    }
  }
}

// ---------------- launcher ----------------

extern "C" void kernel_launch(void* const* d_in, const int* in_sizes, int n_in,
                              void* d_out, int out_size, void* d_ws, size_t ws_size,
                              hipStream_t stream) {
  const float* x   = (const float*)d_in[0];
  const float* h   = (const float*)d_in[1];
  const float* Wl  = (const float*)d_in[2];  // [4,2560,2560]
  const float* bl  = (const float*)d_in[3];  // [4,2560]
  const float* Wih = (const float*)d_in[4];  // [2048,2560]
  const float* bih = (const float*)d_in[5];  // [2048]
  const float* Wio = (const float*)d_in[6];  // [512,2560]
  const float* bio = (const float*)d_in[7];  // [512]

  unsigned short* ws   = (unsigned short*)d_ws;
  unsigned short* Wlp  = ws;                                   // packed, 4*2560*2560
  unsigned short* Whp  = Wlp + (long)NLAYER * INNER * INNER;   // packed fused heads
  unsigned short* act0 = Whp + (long)INNER * INNER;
  unsigned short* act1 = act0 + (long)BATCH * INNER;

  // pack fp32 weights -> fragment-linear bf16. Wl as one 10240-row matrix
  // (layer l occupies n16 in [160l,160(l+1)) -> dst offset l*INNER*INNER).
  pack_w<<<2048, 256, 0, stream>>>(Wl, Wl, NLAYER * INNER, NLAYER * INNER, Wlp);
  // fused heads: rows 0-511 = Wio, 512-2559 = Wih
  pack_w<<<512, 256, 0, stream>>>(Wio, Wih, OUT_SZ, INNER, Whp);
  build_combined<<<2048, 256, 0, stream>>>(x, h, act0);

  // 4 square layers, ping-pong
  unsigned short* a_in = act0;
  unsigned short* a_out = act1;
  for (int l = 0; l < NLAYER; ++l) {
    gemm_bp<0><<<512, 256, 0, stream>>>(a_in, Wlp + (long)l * INNER * INNER,
                                        bl + (long)l * INNER, nullptr, a_out);
    unsigned short* t = a_in; a_in = a_out; a_out = t;
  }

  // fused heads: output (cols 0-511) + tanh hidden (cols 512-2559)
  gemm_bp<1><<<512, 256, 0, stream>>>(a_in, Whp, bio, bih, d_out);
}